// Round 4
// baseline (56.200 us; speedup 1.0000x reference)
//
#include <hip/hip_runtime.h>

// out[n,i,h,j] = x[n,h,j]*w1 + (b - x[n,h,idx(i,j)])*w2
// idx(i,j) = j if j < i else j - i
// B=4, H=256, W=256; out shape (B, W=i, H=h, W=j) = 4*256^3 f32.
//
// Shifted row fetched via TWO aligned L2-hit float4 loads (A at lane-q,
// B at lane-q-1, clamped; clamped lanes provably fully masked by c[k]),
// sub-4 shift r resolved by register renaming (block-uniform template).
// No DS ops at all. Output stored nontemporally (streaming, 268 MB).

typedef float f4 __attribute__((ext_vector_type(4)));

template <int R>
__device__ __forceinline__ void run_rows(
    const f4* __restrict__ xa,   // xrow4 + lane
    const f4* __restrict__ xA,   // xrow4 + max(lane-q, 0)
    const f4* __restrict__ xB,   // xrow4 + max(lane-q-1, 0)
    f4* __restrict__ oout,
    bool c0, bool c1, bool c2, bool c3,
    float w1, float w2, float bb) {
  #pragma unroll
  for (int it = 0; it < 8; ++it) {
    f4 a = xa[it * 64];
    f4 A = xA[it * 64];
    f4 B = xB[it * 64];

    float s0, s1, s2, s3;
    if constexpr (R == 0)      { s0 = A.x; s1 = A.y; s2 = A.z; s3 = A.w; }
    else if constexpr (R == 1) { s0 = B.w; s1 = A.x; s2 = A.y; s3 = A.z; }
    else if constexpr (R == 2) { s0 = B.z; s1 = B.w; s2 = A.x; s3 = A.y; }
    else                       { s0 = B.y; s1 = B.z; s2 = B.w; s3 = A.x; }

    float t0 = c0 ? a.x : s0;
    float t1 = c1 ? a.y : s1;
    float t2 = c2 ? a.z : s2;
    float t3 = c3 ? a.w : s3;

    f4 o;
    o.x = a.x * w1 + (bb - t0) * w2;
    o.y = a.y * w1 + (bb - t1) * w2;
    o.z = a.z * w1 + (bb - t2) * w2;
    o.w = a.w * w1 + (bb - t3) * w2;

    __builtin_nontemporal_store(o, oout + it * 64);
  }
}

__global__ __launch_bounds__(256) void overlap_kernel(
    const float* __restrict__ x,
    const float* __restrict__ bp,
    const float* __restrict__ w1p,
    const float* __restrict__ w2p,
    float* __restrict__ out) {
  const float bb = bp[0];
  const float w1 = w1p[0];
  const float w2 = w2p[0];

  // grid = 4 * 256 * 8 = 8192 blocks; bl = ((n*256 + i)*8 + hc)
  int bl = blockIdx.x;
  int hc = bl & 7;
  int i  = (bl >> 3) & 255;   // block-uniform shift
  int n  = bl >> 11;

  int lane  = threadIdx.x & 63;
  int w     = threadIdx.x >> 6;            // wave id 0..3
  int hbase = (hc << 5) + (w << 3);        // 8 consecutive h rows per wave
  int j0    = lane << 2;

  int q = i >> 2;
  int r = i & 3;
  int la = lane - q;     if (la < 0) la = 0;   // clamped lanes fully masked
  int lb = lane - q - 1; if (lb < 0) lb = 0;

  bool c0 = (j0 + 0) < i;
  bool c1 = (j0 + 1) < i;
  bool c2 = (j0 + 2) < i;
  bool c3 = (j0 + 3) < i;

  const f4* xrow4 = reinterpret_cast<const f4*>(x + (n << 16) + (hbase << 8));
  const f4* xa = xrow4 + lane;
  const f4* xA = xrow4 + la;
  const f4* xB = xrow4 + lb;
  f4* oout = reinterpret_cast<f4*>(out) +
             (((n << 8) + i) << 14) + (hbase << 6) + lane;

  switch (r) {  // block-uniform, no divergence
    case 0: run_rows<0>(xa, xA, xB, oout, c0, c1, c2, c3, w1, w2, bb); break;
    case 1: run_rows<1>(xa, xA, xB, oout, c0, c1, c2, c3, w1, w2, bb); break;
    case 2: run_rows<2>(xa, xA, xB, oout, c0, c1, c2, c3, w1, w2, bb); break;
    default: run_rows<3>(xa, xA, xB, oout, c0, c1, c2, c3, w1, w2, bb); break;
  }
}

extern "C" void kernel_launch(void* const* d_in, const int* in_sizes, int n_in,
                              void* d_out, int out_size, void* d_ws, size_t ws_size,
                              hipStream_t stream) {
  const float* x  = (const float*)d_in[0];
  const float* b  = (const float*)d_in[1];
  const float* w1 = (const float*)d_in[2];
  const float* w2 = (const float*)d_in[3];
  float* out = (float*)d_out;

  overlap_kernel<<<8192, 256, 0, stream>>>(x, b, w1, w2, out);
}

// Round 5
// 46.497 us; speedup vs baseline: 1.2087x; 1.2087x over previous
//
#include <hip/hip_runtime.h>

// out[n,i,h,j] = x[n,h,j]*w1 + (b - x[n,h,idx(i,j)])*w2
// idx(i,j) = j if j < i else j - i
// B=4, H=256, W=256; out shape (B, W=i, H=h, W=j) = 4*256^3 f32.
//
// Block owns fixed (n, i, h-chunk): i-dependent shuffle setup (q, r, srcA/B,
// compare masks) hoisted out of the loop entirely (r-path chosen once, 4
// bpermutes/iter). Inner loop walks 8 consecutive h rows per wave -> per-wave
// 8 KB contiguous stores, per-block 32 KB, consecutive blocks contiguous:
// linear streaming write sweep. x row reloads are L2 hits (x = 1 MB total).
//
// R4 post-mortem: nontemporal stores + load-based shift regressed (56 µs);
// this shuffle + normal-store version is the measured optimum (46.5 µs,
// ~4% above the fillBuffer-calibrated write ceiling incl. launch ramp).

template <int R>
__device__ __forceinline__ void run_rows(
    const float4* __restrict__ xin,   // = (float4*)xrow_base + lane
    float4* __restrict__ oout,        // = out4 base + lane
    int srcA, int srcB,
    bool c0, bool c1, bool c2, bool c3,
    float w1, float w2, float bb) {
  #pragma unroll
  for (int it = 0; it < 8; ++it) {
    float4 a = xin[it * 64];  // next h row, coalesced 1 KB, L2-hit

    float s0, s1, s2, s3;
    if constexpr (R == 0) {
      s0 = __shfl(a.x, srcA, 64); s1 = __shfl(a.y, srcA, 64);
      s2 = __shfl(a.z, srcA, 64); s3 = __shfl(a.w, srcA, 64);
    } else if constexpr (R == 1) {
      s0 = __shfl(a.w, srcB, 64); s1 = __shfl(a.x, srcA, 64);
      s2 = __shfl(a.y, srcA, 64); s3 = __shfl(a.z, srcA, 64);
    } else if constexpr (R == 2) {
      s0 = __shfl(a.z, srcB, 64); s1 = __shfl(a.w, srcB, 64);
      s2 = __shfl(a.x, srcA, 64); s3 = __shfl(a.y, srcA, 64);
    } else {
      s0 = __shfl(a.y, srcB, 64); s1 = __shfl(a.z, srcB, 64);
      s2 = __shfl(a.w, srcB, 64); s3 = __shfl(a.x, srcA, 64);
    }

    float t0 = c0 ? a.x : s0;
    float t1 = c1 ? a.y : s1;
    float t2 = c2 ? a.z : s2;
    float t3 = c3 ? a.w : s3;

    float4 o;
    o.x = a.x * w1 + (bb - t0) * w2;
    o.y = a.y * w1 + (bb - t1) * w2;
    o.z = a.z * w1 + (bb - t2) * w2;
    o.w = a.w * w1 + (bb - t3) * w2;

    oout[it * 64] = o;
  }
}

__global__ __launch_bounds__(256) void overlap_kernel(
    const float* __restrict__ x,
    const float* __restrict__ bp,
    const float* __restrict__ w1p,
    const float* __restrict__ w2p,
    float* __restrict__ out) {
  const float bb = bp[0];
  const float w1 = w1p[0];
  const float w2 = w2p[0];

  // grid = 4 * 256 * 8 = 8192 blocks; bl = ((n*256 + i)*8 + hc)
  int bl = blockIdx.x;
  int hc = bl & 7;
  int i  = (bl >> 3) & 255;   // block-uniform shift
  int n  = bl >> 11;

  int lane  = threadIdx.x & 63;
  int w     = threadIdx.x >> 6;            // wave id 0..3
  int hbase = (hc << 5) + (w << 3);        // 8 consecutive h rows per wave
  int j0    = lane << 2;

  int q = i >> 2;
  int r = i & 3;
  int srcA = lane - q;
  int srcB = srcA - 1;

  bool c0 = (j0 + 0) < i;
  bool c1 = (j0 + 1) < i;
  bool c2 = (j0 + 2) < i;
  bool c3 = (j0 + 3) < i;

  const float4* xin = reinterpret_cast<const float4*>(x + (n << 16) + (hbase << 8)) + lane;
  float4* oout = reinterpret_cast<float4*>(out) +
                 (((n << 8) + i) << 14) + (hbase << 6) + lane;

  switch (r) {  // block-uniform, no divergence
    case 0: run_rows<0>(xin, oout, srcA, srcB, c0, c1, c2, c3, w1, w2, bb); break;
    case 1: run_rows<1>(xin, oout, srcA, srcB, c0, c1, c2, c3, w1, w2, bb); break;
    case 2: run_rows<2>(xin, oout, srcA, srcB, c0, c1, c2, c3, w1, w2, bb); break;
    default: run_rows<3>(xin, oout, srcA, srcB, c0, c1, c2, c3, w1, w2, bb); break;
  }
}

extern "C" void kernel_launch(void* const* d_in, const int* in_sizes, int n_in,
                              void* d_out, int out_size, void* d_ws, size_t ws_size,
                              hipStream_t stream) {
  const float* x  = (const float*)d_in[0];
  const float* b  = (const float*)d_in[1];
  const float* w1 = (const float*)d_in[2];
  const float* w2 = (const float*)d_in[3];
  float* out = (float*)d_out;

  overlap_kernel<<<8192, 256, 0, stream>>>(x, b, w1, w2, out);
}